// Round 10
// baseline (484.843 us; speedup 1.0000x reference)
//
#include <hip/hip_runtime.h>
#include <math.h>

using f16 = _Float16;
using f16x2 = __attribute__((ext_vector_type(2))) _Float16;
using f16x4 = __attribute__((ext_vector_type(4))) _Float16;
using f16x8 = __attribute__((ext_vector_type(8))) _Float16;
using f32x4 = __attribute__((ext_vector_type(4))) float;
using h16x2 = __attribute__((ext_vector_type(2))) __fp16;

static constexpr int B_ = 2, S_ = 2048, H_ = 1024, NH_ = 16, HD_ = 64;
static constexpr int M_ = B_ * S_;                 // 4096 rows of X
static constexpr size_t SZX = (size_t)M_ * H_;     // 4,194,304 elems
static constexpr float LOG2E = 1.4426950408889634f;

__device__ __forceinline__ f32x4 mfma16(f16x8 a, f16x8 b, f32x4 c) {
    return __builtin_amdgcn_mfma_f32_16x16x32_f16(a, b, c, 0, 0, 0);
}
__device__ __forceinline__ f16x2 cvt_pk(float a, float b) {
    h16x2 r = __builtin_amdgcn_cvt_pkrtz(a, b);
    return __builtin_bit_cast(f16x2, r);
}

// async 16B global -> LDS (wave-uniform LDS base + lane*16)
typedef const __attribute__((address_space(1))) unsigned int* gas_t;
typedef __attribute__((address_space(3))) unsigned int* las_t;
__device__ __forceinline__ void load16_lds(const void* g, void* lds_base) {
    __builtin_amdgcn_global_load_lds((gas_t)g, (las_t)lds_base, 16, 0, 0);
}

// ---------------- merged Q/K/V projection, f32 in, K-step 32, 4 blk/CU ------
// 1D grid 768, XCD-chunked decode: o=(lid%8)*96+lid/8; which=o>>8,
// y=(o>>3)&31, col=o&7 -> co-resident blocks on an XCD share X row-panels
// (512KB, L2-fits) and cycle all of W (4MB = L2) for reuse.
// K-step 32: LDS 32KB -> 4 blocks/CU (16 waves) hides staging latency by TLP.
// Staging: per lane 8 f32 x2 matrices -> RNE cvt -> ds_write_b128 at
// base+lane*16 (linear). Stored col-block j holds global block j^(row&3);
// frag read ph=(quad^(c&3))*8 inverts it; per-128B-line slots all distinct
// -> conflict-free (same structure as the K-64 layout that measured 0).
__global__ __launch_bounds__(256, 4) void proj_kernel(
    const float* __restrict__ Xq, const float* __restrict__ Xk, const float* __restrict__ Xv,
    const float* __restrict__ Wq, const float* __restrict__ Wk, const float* __restrict__ Wv,
    const float* __restrict__ bq, const float* __restrict__ bk, const float* __restrict__ bv,
    f16* __restrict__ q, f16* __restrict__ k, f16* __restrict__ vt) {
    __shared__ alignas(16) f16 sX[2][128][32];
    __shared__ alignas(16) f16 sW[2][128][32];
    const int t = threadIdx.x, w = t >> 6, lane = t & 63, c = lane & 15, quad = lane >> 4;
    const int lid = blockIdx.x;
    const int o = (lid & 7) * 96 + (lid >> 3);     // bijective XCD chunking
    const int which = o >> 8;
    const int row0 = ((o >> 3) & 31) * 128;
    const int col0 = (o & 7) * 128;
    const float* X = which == 0 ? Xq : which == 1 ? Xk : Xv;
    const float* W = which == 0 ? Wq : which == 1 ? Wk : Wv;
    const int wm = (w & 1) * 64, wn = (w >> 1) * 64;
    f32x4 acc[4][4] = {};

    const int lr = lane >> 2, lc = lane & 3;       // 16 rows x 4 col-blocks
    const int G = lc ^ (lr & 3);                   // global col-block fetched
    f32x4 rx[4], rw[4];                            // one K-step tile in regs

    auto issue = [&](int kstep) {
        const int k0 = kstep * 32;
#pragma unroll
        for (int i = 0; i < 2; ++i) {
            const float* gx = X + (size_t)(row0 + 32 * w + 16 * i + lr) * H_ + k0 + G * 8;
            const float* gw = W + (size_t)(col0 + 32 * w + 16 * i + lr) * H_ + k0 + G * 8;
            rx[2 * i] = *(const f32x4*)gx;
            rx[2 * i + 1] = *(const f32x4*)(gx + 4);
            rw[2 * i] = *(const f32x4*)gw;
            rw[2 * i + 1] = *(const f32x4*)(gw + 4);
        }
    };
    auto write_cvt = [&](int buf) {                // regs -> f16 -> LDS (RNE)
#pragma unroll
        for (int i = 0; i < 2; ++i) {
            int R = 32 * w + 16 * i + lr;
            f16x8 hx, hw;
#pragma unroll
            for (int j = 0; j < 4; ++j) {
                hx[j] = (f16)rx[2 * i][j];
                hx[4 + j] = (f16)rx[2 * i + 1][j];
                hw[j] = (f16)rw[2 * i][j];
                hw[4 + j] = (f16)rw[2 * i + 1][j];
            }
            *(f16x8*)&sX[buf][R][lc * 8] = hx;
            *(f16x8*)&sW[buf][R][lc * 8] = hw;
        }
    };

    issue(0);
    write_cvt(0);          // compiler inserts the vmcnt wait for rx/rw
    issue(1);              // tile 1 in flight across the barrier
    asm volatile("s_waitcnt lgkmcnt(0)" ::: "memory");
    asm volatile("s_barrier" ::: "memory");

    for (int kt = 0; kt < 32; ++kt) {
        const int cur = kt & 1;
        if (kt < 31) write_cvt(cur ^ 1);   // tile kt+1 -> buffer freed @ kt-1
        if (kt < 30) issue(kt + 2);        // regs reused after cvt consumed them
        const int ph = (quad ^ (c & 3)) * 8;
        f16x8 wf[4], xf[4];
#pragma unroll
        for (int gg = 0; gg < 4; ++gg) {
            wf[gg] = *(const f16x8*)&sW[cur][wn + gg * 16 + c][ph];
            xf[gg] = *(const f16x8*)&sX[cur][wm + gg * 16 + c][ph];
        }
        if (which == 2) {
#pragma unroll
            for (int mg = 0; mg < 4; ++mg)
#pragma unroll
                for (int ng = 0; ng < 4; ++ng)
                    acc[mg][ng] = mfma16(xf[mg], wf[ng], acc[mg][ng]);
        } else {
#pragma unroll
            for (int mg = 0; mg < 4; ++mg)
#pragma unroll
                for (int ng = 0; ng < 4; ++ng)
                    acc[mg][ng] = mfma16(wf[ng], xf[mg], acc[mg][ng]);
        }
        if (kt < 31) {
            // this wave's frag ds_reads + staging ds_writes drained, then sync
            asm volatile("s_waitcnt lgkmcnt(0)" ::: "memory");
            asm volatile("s_barrier" ::: "memory");
        }
    }

    if (which < 2) {
        const float* bias = which ? bk : bq;
        f16* O = which ? k : q;
        const float scale = which ? 1.0f : (LOG2E * 0.125f);
#pragma unroll
        for (int ng = 0; ng < 4; ++ng) {
            int col4 = col0 + wn + ng * 16 + quad * 4;
            f32x4 bv_ = *(const f32x4*)(bias + col4);
            int hh = col4 >> 6, d = col4 & 63;
#pragma unroll
            for (int mg = 0; mg < 4; ++mg) {
                int rowg = row0 + wm + mg * 16 + c;
                int bb = rowg >> 11, ss = rowg & (S_ - 1);
                f16x4 ov;
#pragma unroll
                for (int r = 0; r < 4; ++r) ov[r] = (f16)((acc[mg][ng][r] + bv_[r]) * scale);
                *(f16x4*)(O + ((size_t)(bb * NH_ + hh) * S_ + ss) * HD_ + d) = ov;
            }
        }
    } else {
#pragma unroll
        for (int ng = 0; ng < 4; ++ng) {
            int col = col0 + wn + ng * 16 + c;
            float bv_ = bv[col];
            int hh = col >> 6, d = col & 63;
#pragma unroll
            for (int mg = 0; mg < 4; ++mg) {
                int rbase = row0 + wm + mg * 16 + quad * 4;
                int bb = rbase >> 11, ss = rbase & (S_ - 1);
                int sl = ss & 31;   // 4-aligned: k1k0 = 0
                int pp = (ss & ~31) | (((sl >> 4) & 1) << 2) | (((sl >> 2) & 1) << 3) | (((sl >> 3) & 1) << 4);
                f16x4 ov;
#pragma unroll
                for (int r = 0; r < 4; ++r) ov[r] = (f16)(acc[mg][ng][r] + bv_);
                *(f16x4*)(vt + ((size_t)(bb * NH_ + hh) * HD_ + d) * S_ + pp) = ov;
            }
        }
    }
}

// ---------------- flash attention, split-KV, s-dies-early pipeline ----------
// (unchanged from round 9 — the control kernel.)
__global__ __launch_bounds__(512, 2) void attn_kernel(
    const f16* __restrict__ Q, const f16* __restrict__ K,
    const f16* __restrict__ VT, const float* __restrict__ mask,
    float* __restrict__ out) {
    __shared__ alignas(128) unsigned char smem[74752];

    const int t = threadIdx.x, w = t >> 6, lane = t & 63, c = lane & 15, quad = lane >> 4;
    const int g = w >> 2, ww = w & 3;
    const int qt = blockIdx.x, bh = blockIdx.y;
    const int b = bh >> 4, hh = bh & 15;
    const size_t qkb = (size_t)bh * S_ * HD_;
    const size_t vtb = (size_t)bh * HD_ * S_;

    unsigned char* gmem = smem + g * 36864;
    float* maskL = (float*)(gmem + 32768);   // raw mask values
    float* cml = (float*)(smem + 73728);
    float* cO = (float*)smem;

    // Q fragments (registers, whole K-loop)
    f16x8 qf[2][2];
#pragma unroll
    for (int nb = 0; nb < 2; ++nb)
#pragma unroll
        for (int ch = 0; ch < 2; ++ch) {
            int qq = qt * 128 + ww * 32 + nb * 16 + c;
            qf[nb][ch] = *(const f16x8*)(Q + qkb + (size_t)qq * HD_ + ch * 32 + quad * 8);
        }

    const int lr = lane >> 3;                  // 0..7
    const int lcb = (lane & 7) ^ lr;           // XOR-swizzled col-block
    const f16* kbase = K + qkb + (size_t)(8 * ww + lr) * HD_ + lcb * 8;
    const f16* vtbase = VT + vtb + (size_t)(8 * ww + lr) * S_ + lcb * 8;

    // stage this group's mask half (raw f32) into LDS, once
    load16_lds(mask + b * S_ + g * 1024 + ww * 256, gmem + 32768 + ww * 1024);

    auto stageK = [&](int j) {     // K tile j -> Kbuf[j&1]  (2 loads)
        const int kt2 = g * 16 + j;
        f16* dK = (f16*)(gmem + (j & 1) * 8192) + 8 * ww * 64;
        load16_lds(kbase + (size_t)(kt2 * 64) * HD_, dK);
        load16_lds(kbase + (size_t)(kt2 * 64 + 32) * HD_, dK + 32 * 64);
    };
    auto stageV = [&](int j) {     // V tile j -> Vbuf[j&1]  (2 loads)
        const int kt2 = g * 16 + j;
        f16* dV = (f16*)(gmem + 16384 + (j & 1) * 8192) + 8 * ww * 64;
        load16_lds(vtbase + kt2 * 64, dV);
        load16_lds(vtbase + (size_t)32 * S_ + kt2 * 64, dV + 32 * 64);
    };

    // ones-row A fragment for the l accumulator (row d=64 of virtual V^T)
    const f16 one_ = (c == 0) ? (f16)1 : (f16)0;
    const f16x8 af_ones = {one_, one_, one_, one_, one_, one_, one_, one_};

    f32x4 o[5][2] = {};   // db=4 row holds l at (quad==0, elem 0)
    float m_i[2] = {-INFINITY, -INFINITY};
    f16x4 pf[2][4][2];    // static double-buffered P (parity-indexed)

    auto qk_step = [&](int j, f32x4(&s)[4][2]) {   // S^T(tile j) = mask*log2e + K·Q^T
        const f16(*sKc)[64] = (const f16(*)[64])(gmem + (j & 1) * 8192);
#pragma unroll
        for (int mb = 0; mb < 4; ++mb) {
            f32x4 mv = *(const f32x4*)(maskL + j * 64 + mb * 16 + quad * 4);
            mv *= LOG2E;
            s[mb][0] = mv;
            s[mb][1] = mv;
        }
#pragma unroll
        for (int ch = 0; ch < 2; ++ch) {
            const int ph = ((ch * 4 + quad) ^ (c & 7)) * 8;
#pragma unroll
            for (int mb = 0; mb < 4; ++mb) {
                f16x8 ah = *(const f16x8*)&sKc[mb * 16 + c][ph];
                s[mb][0] = mfma16(ah, qf[0][ch], s[mb][0]);
                s[mb][1] = mfma16(ah, qf[1][ch], s[mb][1]);
            }
        }
    };
    auto pv_step = [&](int j, f16x4(&pin)[4][2]) { // O^T += V^T(tile j)·P^T
        const f16(*sVc)[64] = (const f16(*)[64])(gmem + 16384 + (j & 1) * 8192);
#pragma unroll
        for (int kcc = 0; kcc < 2; ++kcc) {
            const int blk = kcc * 4 + quad;
            const int pblk = (blk ^ c) & 7;
            f16x8 bf0 = __builtin_shufflevector(pin[2 * kcc][0], pin[2 * kcc + 1][0],
                                                0, 1, 2, 3, 4, 5, 6, 7);
            f16x8 bf1 = __builtin_shufflevector(pin[2 * kcc][1], pin[2 * kcc + 1][1],
                                                0, 1, 2, 3, 4, 5, 6, 7);
#pragma unroll
            for (int db = 0; db < 5; ++db) {
                f16x8 af = (db == 4) ? af_ones : *(const f16x8*)&sVc[db * 16 + c][pblk * 8];
                o[db][0] = mfma16(af, bf0, o[db][0]);
                o[db][1] = mfma16(af, bf1, o[db][1]);
            }
        }
    };
    auto softmax_step = [&](f32x4(&s)[4][2], f16x4(&pout)[4][2]) {
        float rloc[2];
#pragma unroll
        for (int nb = 0; nb < 2; ++nb) {
            float a0 = fmaxf(fmaxf(s[0][nb][0], s[0][nb][1]), s[0][nb][2]);
            float a1 = fmaxf(fmaxf(s[0][nb][3], s[1][nb][0]), s[1][nb][1]);
            float a2 = fmaxf(fmaxf(s[1][nb][2], s[1][nb][3]), s[2][nb][0]);
            float a3 = fmaxf(fmaxf(s[2][nb][1], s[2][nb][2]), s[2][nb][3]);
            float a4 = fmaxf(fmaxf(s[3][nb][0], s[3][nb][1]), s[3][nb][2]);
            float b0 = fmaxf(fmaxf(a0, a1), a2);
            float b1 = fmaxf(fmaxf(a3, a4), s[3][nb][3]);
            rloc[nb] = fmaxf(b0, b1);
        }
        if (__any(rloc[0] > m_i[0] + 8.f || rloc[1] > m_i[1] + 8.f)) {
#pragma unroll
            for (int nb = 0; nb < 2; ++nb) {
                float rm = rloc[nb];
                rm = fmaxf(rm, __shfl_xor(rm, 16));
                rm = fmaxf(rm, __shfl_xor(rm, 32));
                float mnew = fmaxf(m_i[nb], rm);
                float alpha = __builtin_amdgcn_exp2f(m_i[nb] - mnew);  // first: 0
                m_i[nb] = mnew;
#pragma unroll
                for (int db = 0; db < 5; ++db) o[db][nb] *= alpha;
            }
        }
#pragma unroll
        for (int nb = 0; nb < 2; ++nb) {
            const float m0 = m_i[nb];
#pragma unroll
            for (int mb = 0; mb < 4; ++mb) {
                f16x2 e01 = cvt_pk(__builtin_amdgcn_exp2f(s[mb][nb][0] - m0),
                                   __builtin_amdgcn_exp2f(s[mb][nb][1] - m0));
                f16x2 e23 = cvt_pk(__builtin_amdgcn_exp2f(s[mb][nb][2] - m0),
                                   __builtin_amdgcn_exp2f(s[mb][nb][3] - m0));
                pout[mb][nb] = __builtin_shufflevector(e01, e23, 0, 1, 2, 3);
            }
        }
    };

    // ---- prologue: stage 0,1; softmax(0) -> pf[0] ----
    stageK(0); stageV(0); stageK(1); stageV(1);
    asm volatile("s_waitcnt vmcnt(2)" ::: "memory");
    asm volatile("s_barrier" ::: "memory");
    {
        f32x4 s0[4][2];
        qk_step(0, s0);
        softmax_step(s0, pf[0]);
    }
    asm volatile("s_barrier" ::: "memory");

    // ---- main loop j = 0..13 (fully unrolled: static parity) ----
#pragma unroll
    for (int j = 0; j < 14; ++j) {
        stageK(j + 2);                        // Kbuf[j&1], freed by last barrier
        f32x4 s[4][2];
        qk_step(j + 1, s);                    // Kbuf[(j+1)&1]
        softmax_step(s, pf[(j + 1) & 1]);     // s dies here
        pv_step(j, pf[j & 1]);                // Vbuf[j&1]
        asm volatile("s_barrier" ::: "memory");
        stageV(j + 2);                        // Vbuf[j&1]
        asm volatile("s_waitcnt vmcnt(2)" ::: "memory");
        asm volatile("s_barrier" ::: "memory");
    }
    // ---- j = 14: no further staging ----
    {
        f32x4 s[4][2];
        qk_step(15, s);
        softmax_step(s, pf[1]);
        pv_step(14, pf[0]);
        asm volatile("s_barrier" ::: "memory");
        asm volatile("s_waitcnt vmcnt(0)" ::: "memory");   // V15 lands
        asm volatile("s_barrier" ::: "memory");
    }
    // ---- epilogue: last PV ----
    pv_step(15, pf[1]);

    float l_i[2];
    l_i[0] = __shfl(o[4][0][0], c);
    l_i[1] = __shfl(o[4][1][0], c);

    __syncthreads();   // PV(15) LDS reads done before aliasing cO over bufs
    if (g == 1) {
#pragma unroll
        for (int nb = 0; nb < 2; ++nb) {
            int ql = ww * 32 + nb * 16 + c;
            if (quad == 0) { cml[ql] = m_i[nb]; cml[128 + ql] = l_i[nb]; }
#pragma unroll
            for (int db = 0; db < 4; ++db) {
                int d4 = db * 4 + quad;
                *(f32x4*)&cO[(ql * 16 + (d4 ^ (ql & 15))) << 2] = o[db][nb];
            }
        }
    }
    __syncthreads();
    if (g == 0) {
#pragma unroll
        for (int nb = 0; nb < 2; ++nb) {
            int ql = ww * 32 + nb * 16 + c;
            int qq = qt * 128 + ql;
            float m2 = cml[ql], l2 = cml[128 + ql];
            float mm = fmaxf(m_i[nb], m2);
            float a1 = __builtin_amdgcn_exp2f(m_i[nb] - mm);
            float a2 = __builtin_amdgcn_exp2f(m2 - mm);
            float linv = 1.f / (l_i[nb] * a1 + l2 * a2);
#pragma unroll
            for (int db = 0; db < 4; ++db) {
                int d4 = db * 4 + quad;
                f32x4 v2 = *(const f32x4*)&cO[(ql * 16 + (d4 ^ (ql & 15))) << 2];
                f32x4 v = (o[db][nb] * a1 + v2 * a2) * linv;
                *(f32x4*)(out + ((size_t)b * S_ + qq) * H_ + hh * 64 + db * 16 + quad * 4) = v;
            }
        }
    }
}

// ---------------- launch ----------------
extern "C" void kernel_launch(void* const* d_in, const int* in_sizes, int n_in,
                              void* d_out, int out_size, void* d_ws, size_t ws_size,
                              hipStream_t stream) {
    const float* query = (const float*)d_in[0];
    const float* key   = (const float*)d_in[1];
    const float* value = (const float*)d_in[2];
    const float* mask  = (const float*)d_in[3];
    const float* Wq    = (const float*)d_in[4];
    const float* bq    = (const float*)d_in[5];
    const float* Wk    = (const float*)d_in[6];
    const float* bk    = (const float*)d_in[7];
    const float* Wv    = (const float*)d_in[8];
    const float* bv    = (const float*)d_in[9];
    float* out = (float*)d_out;

    f16* p = (f16*)d_ws;
    f16* q  = p; p += SZX; f16* k  = p; p += SZX; f16* vt = p; p += SZX;

    proj_kernel<<<768, 256, 0, stream>>>(query, key, value, Wq, Wk, Wv,
                                         bq, bk, bv, q, k, vt);

    dim3 ag(S_ / 128, B_ * NH_);
    attn_kernel<<<ag, 512, 0, stream>>>(q, k, vt, mask, out);
}

// Round 11
// 202.150 us; speedup vs baseline: 2.3984x; 2.3984x over previous
//
#include <hip/hip_runtime.h>
#include <math.h>

using f16 = _Float16;
using f16x2 = __attribute__((ext_vector_type(2))) _Float16;
using f16x4 = __attribute__((ext_vector_type(4))) _Float16;
using f16x8 = __attribute__((ext_vector_type(8))) _Float16;
using f32x4 = __attribute__((ext_vector_type(4))) float;
using h16x2 = __attribute__((ext_vector_type(2))) __fp16;

static constexpr int B_ = 2, S_ = 2048, H_ = 1024, NH_ = 16, HD_ = 64;
static constexpr int M_ = B_ * S_;                 // 4096 rows of X
static constexpr size_t SZX = (size_t)M_ * H_;     // 4,194,304 elems
static constexpr size_t SZW = (size_t)H_ * H_;     // 1,048,576 elems
static constexpr float LOG2E = 1.4426950408889634f;

__device__ __forceinline__ f32x4 mfma16(f16x8 a, f16x8 b, f32x4 c) {
    return __builtin_amdgcn_mfma_f32_16x16x32_f16(a, b, c, 0, 0, 0);
}
__device__ __forceinline__ f16x2 cvt_pk(float a, float b) {
    h16x2 r = __builtin_amdgcn_cvt_pkrtz(a, b);
    return __builtin_bit_cast(f16x2, r);
}

// async 16B global -> LDS (wave-uniform LDS base + lane*16)
typedef const __attribute__((address_space(1))) unsigned int* gas_t;
typedef __attribute__((address_space(3))) unsigned int* las_t;
__device__ __forceinline__ void load16_lds(const void* g, void* lds_base) {
    __builtin_amdgcn_global_load_lds((gas_t)g, (las_t)lds_base, 16, 0, 0);
}

// ---------------- prep: fp32->fp16 x6 tensors + mask*log2e, one launch -----
// (exact kernel from the 201.8 µs run)
__global__ __launch_bounds__(256) void prep_kernel(
    const float* __restrict__ xqf, const float* __restrict__ xkf, const float* __restrict__ xvf,
    const float* __restrict__ wqf, const float* __restrict__ wkf, const float* __restrict__ wvf,
    const float* __restrict__ mask,
    f16* __restrict__ xq, f16* __restrict__ xk, f16* __restrict__ xv,
    f16* __restrict__ wq, f16* __restrict__ wk, f16* __restrict__ wv,
    float* __restrict__ mask_s) {
    constexpr int NX = (int)(SZX / 4);   // 1<<20
    constexpr int NW = (int)(SZW / 4);   // 1<<18
    static_assert(NX == (1 << 20) && NW == (1 << 18), "shift assumptions");
    int i = blockIdx.x * 256 + threadIdx.x;
    const float* src;
    f16* dst;
    int j;
    if (i < 3 * NX) {
        int z = i >> 20;
        j = i & (NX - 1);
        src = z == 0 ? xqf : z == 1 ? xkf : xvf;
        dst = z == 0 ? xq : z == 1 ? xk : xv;
    } else if (i < 3 * NX + 3 * NW) {
        int r = i - 3 * NX;
        int z = r >> 18;
        j = r & (NW - 1);
        src = z == 0 ? wqf : z == 1 ? wkf : wvf;
        dst = z == 0 ? wq : z == 1 ? wk : wv;
    } else {
        int r = i - (3 * NX + 3 * NW);
        if (r < B_ * S_ / 4) {
            f32x4 m = ((const f32x4*)mask)[r];
            ((f32x4*)mask_s)[r] = m * LOG2E;
        }
        return;
    }
    f32x4 v = ((const f32x4*)src)[j];
    f16x4 h;
#pragma unroll
    for (int r = 0; r < 4; ++r) h[r] = (f16)v[r];
    ((f16x4*)dst)[j] = h;
}

// ---------------- merged Q/K/V projection (exact kernel from the 201.8 run) -
// which = blockIdx.x>>3 in {0:q, 1:k, 2:v}.
// q/k path: O^T = W·X^T orientation -> [B,NH,S,HD], q pre-scaled log2e/8.
// v path: X·W^T orientation, transposed permuted out vt[bh][d][s'] with
// s' bit-permutation within 32-groups: p1p0=k1k0, p2=k4, p3=k2, p4=k3.
// Single-buffered 32KB LDS (3 blocks/CU at grid 768), gload_lds staging.
__global__ __launch_bounds__(256, 2) void proj_kernel(
    const f16* __restrict__ xq, const f16* __restrict__ xk, const f16* __restrict__ xv,
    const f16* __restrict__ wq, const f16* __restrict__ wk, const f16* __restrict__ wv,
    const float* __restrict__ bq, const float* __restrict__ bk, const float* __restrict__ bv,
    f16* __restrict__ q, f16* __restrict__ k, f16* __restrict__ vt) {
    __shared__ alignas(16) f16 sX[128][64];
    __shared__ alignas(16) f16 sW[128][64];
    const int t = threadIdx.x, w = t >> 6, lane = t & 63, c = lane & 15, quad = lane >> 4;
    const int which = blockIdx.x >> 3;
    const int col0 = (blockIdx.x & 7) * 128;
    const int row0 = blockIdx.y * 128;
    const f16* X = which == 0 ? xq : which == 1 ? xk : xv;
    const f16* W = which == 0 ? wq : which == 1 ? wk : wv;
    const int wm = (w & 1) * 64, wn = (w >> 1) * 64;
    f32x4 acc[4][4] = {};

    for (int k0 = 0; k0 < H_; k0 += 64) {
        if (k0) __syncthreads();
#pragma unroll
        for (int i = 0; i < 4; ++i) {
            int r = 8 * w + 32 * i + (lane >> 3);
            int cb = (lane & 7) ^ ((lane >> 3) & 7);
            load16_lds(X + (size_t)(row0 + r) * H_ + k0 + cb * 8, &sX[8 * w + 32 * i][0]);
            load16_lds(W + (size_t)(col0 + r) * H_ + k0 + cb * 8, &sW[8 * w + 32 * i][0]);
        }
        __syncthreads();
        if (which == 2) {
#pragma unroll
            for (int ks = 0; ks < 2; ++ks) {
                const int ph = ((ks * 4 + quad) ^ (c & 7)) * 8;
                f16x8 wf[4], xf[4];
#pragma unroll
                for (int gg = 0; gg < 4; ++gg) {
                    wf[gg] = *(const f16x8*)&sW[wn + gg * 16 + c][ph];
                    xf[gg] = *(const f16x8*)&sX[wm + gg * 16 + c][ph];
                }
#pragma unroll
                for (int mg = 0; mg < 4; ++mg)
#pragma unroll
                    for (int ng = 0; ng < 4; ++ng)
                        acc[mg][ng] = mfma16(xf[mg], wf[ng], acc[mg][ng]);
            }
        } else {
#pragma unroll
            for (int ks = 0; ks < 2; ++ks) {
                const int ph = ((ks * 4 + quad) ^ (c & 7)) * 8;
                f16x8 wf[4], xf[4];
#pragma unroll
                for (int gg = 0; gg < 4; ++gg) {
                    wf[gg] = *(const f16x8*)&sW[wn + gg * 16 + c][ph];
                    xf[gg] = *(const f16x8*)&sX[wm + gg * 16 + c][ph];
                }
#pragma unroll
                for (int mg = 0; mg < 4; ++mg)
#pragma unroll
                    for (int ng = 0; ng < 4; ++ng)
                        acc[mg][ng] = mfma16(wf[ng], xf[mg], acc[mg][ng]);
            }
        }
    }

    if (which < 2) {
        const float* bias = which ? bk : bq;
        f16* O = which ? k : q;
        const float scale = which ? 1.0f : (LOG2E * 0.125f);
#pragma unroll
        for (int ng = 0; ng < 4; ++ng) {
            int col4 = col0 + wn + ng * 16 + quad * 4;
            f32x4 bv_ = *(const f32x4*)(bias + col4);
            int hh = col4 >> 6, d = col4 & 63;
#pragma unroll
            for (int mg = 0; mg < 4; ++mg) {
                int rowg = row0 + wm + mg * 16 + c;
                int bb = rowg >> 11, ss = rowg & (S_ - 1);
                f16x4 ov;
#pragma unroll
                for (int r = 0; r < 4; ++r) ov[r] = (f16)((acc[mg][ng][r] + bv_[r]) * scale);
                *(f16x4*)(O + ((size_t)(bb * NH_ + hh) * S_ + ss) * HD_ + d) = ov;
            }
        }
    } else {
#pragma unroll
        for (int ng = 0; ng < 4; ++ng) {
            int col = col0 + wn + ng * 16 + c;
            float bv_ = bv[col];
            int hh = col >> 6, d = col & 63;
#pragma unroll
            for (int mg = 0; mg < 4; ++mg) {
                int rbase = row0 + wm + mg * 16 + quad * 4;
                int bb = rbase >> 11, ss = rbase & (S_ - 1);
                int sl = ss & 31;   // 4-aligned: k1k0 = 0
                int pp = (ss & ~31) | (((sl >> 4) & 1) << 2) | (((sl >> 2) & 1) << 3) | (((sl >> 3) & 1) << 4);
                f16x4 ov;
#pragma unroll
                for (int r = 0; r < 4; ++r) ov[r] = (f16)(acc[mg][ng][r] + bv_);
                *(f16x4*)(vt + ((size_t)(bb * NH_ + hh) * HD_ + d) * S_ + pp) = ov;
            }
        }
    }
}

// ---------------- flash attention, split-KV, s-dies-early pipeline ----------
// (exact kernel from the 53.8 µs measurement)
__global__ __launch_bounds__(512, 2) void attn_kernel(
    const f16* __restrict__ Q, const f16* __restrict__ K,
    const f16* __restrict__ VT, const float* __restrict__ mask_s,
    float* __restrict__ out) {
    __shared__ alignas(128) unsigned char smem[74752];

    const int t = threadIdx.x, w = t >> 6, lane = t & 63, c = lane & 15, quad = lane >> 4;
    const int g = w >> 2, ww = w & 3;
    const int qt = blockIdx.x, bh = blockIdx.y;
    const int b = bh >> 4, hh = bh & 15;
    const size_t qkb = (size_t)bh * S_ * HD_;
    const size_t vtb = (size_t)bh * HD_ * S_;

    unsigned char* gmem = smem + g * 36864;
    float* maskL = (float*)(gmem + 32768);
    float* cml = (float*)(smem + 73728);
    float* cO = (float*)smem;

    // Q fragments (registers, whole K-loop)
    f16x8 qf[2][2];
#pragma unroll
    for (int nb = 0; nb < 2; ++nb)
#pragma unroll
        for (int ch = 0; ch < 2; ++ch) {
            int qq = qt * 128 + ww * 32 + nb * 16 + c;
            qf[nb][ch] = *(const f16x8*)(Q + qkb + (size_t)qq * HD_ + ch * 32 + quad * 8);
        }

    const int lr = lane >> 3;                  // 0..7
    const int lcb = (lane & 7) ^ lr;           // XOR-swizzled col-block
    const f16* kbase = K + qkb + (size_t)(8 * ww + lr) * HD_ + lcb * 8;
    const f16* vtbase = VT + vtb + (size_t)(8 * ww + lr) * S_ + lcb * 8;

    // stage this group's mask half (prescaled f32) into LDS, once
    load16_lds(mask_s + b * S_ + g * 1024 + ww * 256, gmem + 32768 + ww * 1024);

    auto stageK = [&](int j) {     // K tile j -> Kbuf[j&1]  (2 loads)
        const int kt2 = g * 16 + j;
        f16* dK = (f16*)(gmem + (j & 1) * 8192) + 8 * ww * 64;
        load16_lds(kbase + (size_t)(kt2 * 64) * HD_, dK);
        load16_lds(kbase + (size_t)(kt2 * 64 + 32) * HD_, dK + 32 * 64);
    };
    auto stageV = [&](int j) {     // V tile j -> Vbuf[j&1]  (2 loads)
        const int kt2 = g * 16 + j;
        f16* dV = (f16*)(gmem + 16384 + (j & 1) * 8192) + 8 * ww * 64;
        load16_lds(vtbase + kt2 * 64, dV);
        load16_lds(vtbase + (size_t)32 * S_ + kt2 * 64, dV + 32 * 64);
    };

    // ones-row A fragment for the l accumulator (row d=64 of virtual V^T)
    const f16 one_ = (c == 0) ? (f16)1 : (f16)0;
    const f16x8 af_ones = {one_, one_, one_, one_, one_, one_, one_, one_};

    f32x4 o[5][2] = {};   // db=4 row holds l at (quad==0, elem 0)
    float m_i[2] = {-INFINITY, -INFINITY};
    f16x4 pf[2][4][2];    // static double-buffered P (parity-indexed)

    auto qk_step = [&](int j, f32x4(&s)[4][2]) {   // S^T(tile j) = mask + K·Q^T
        const f16(*sKc)[64] = (const f16(*)[64])(gmem + (j & 1) * 8192);
#pragma unroll
        for (int mb = 0; mb < 4; ++mb) {
            f32x4 mv = *(const f32x4*)(maskL + j * 64 + mb * 16 + quad * 4);
            s[mb][0] = mv;
            s[mb][1] = mv;
        }
#pragma unroll
        for (int ch = 0; ch < 2; ++ch) {
            const int ph = ((ch * 4 + quad) ^ (c & 7)) * 8;
#pragma unroll
            for (int mb = 0; mb < 4; ++mb) {
                f16x8 ah = *(const f16x8*)&sKc[mb * 16 + c][ph];
                s[mb][0] = mfma16(ah, qf[0][ch], s[mb][0]);
                s[mb][1] = mfma16(ah, qf[1][ch], s[mb][1]);
            }
        }
    };
    auto pv_step = [&](int j, f16x4(&pin)[4][2]) { // O^T += V^T(tile j)·P^T
        const f16(*sVc)[64] = (const f16(*)[64])(gmem + 16384 + (j & 1) * 8192);
#pragma unroll
        for (int kcc = 0; kcc < 2; ++kcc) {
            const int blk = kcc * 4 + quad;
            const int pblk = (blk ^ c) & 7;
            f16x8 bf0 = __builtin_shufflevector(pin[2 * kcc][0], pin[2 * kcc + 1][0],
                                                0, 1, 2, 3, 4, 5, 6, 7);
            f16x8 bf1 = __builtin_shufflevector(pin[2 * kcc][1], pin[2 * kcc + 1][1],
                                                0, 1, 2, 3, 4, 5, 6, 7);
#pragma unroll
            for (int db = 0; db < 5; ++db) {
                f16x8 af = (db == 4) ? af_ones : *(const f16x8*)&sVc[db * 16 + c][pblk * 8];
                o[db][0] = mfma16(af, bf0, o[db][0]);
                o[db][1] = mfma16(af, bf1, o[db][1]);
            }
        }
    };
    auto softmax_step = [&](f32x4(&s)[4][2], f16x4(&pout)[4][2]) {
        float rloc[2];
#pragma unroll
        for (int nb = 0; nb < 2; ++nb) {
            float a0 = fmaxf(fmaxf(s[0][nb][0], s[0][nb][1]), s[0][nb][2]);
            float a1 = fmaxf(fmaxf(s[0][nb][3], s[1][nb][0]), s[1][nb][1]);
            float a2 = fmaxf(fmaxf(s[1][nb][2], s[1][nb][3]), s[2][nb][0]);
            float a3 = fmaxf(fmaxf(s[2][nb][1], s[2][nb][2]), s[2][nb][3]);
            float a4 = fmaxf(fmaxf(s[3][nb][0], s[3][nb][1]), s[3][nb][2]);
            float b0 = fmaxf(fmaxf(a0, a1), a2);
            float b1 = fmaxf(fmaxf(a3, a4), s[3][nb][3]);
            rloc[nb] = fmaxf(b0, b1);
        }
        if (__any(rloc[0] > m_i[0] + 8.f || rloc[1] > m_i[1] + 8.f)) {
#pragma unroll
            for (int nb = 0; nb < 2; ++nb) {
                float rm = rloc[nb];
                rm = fmaxf(rm, __shfl_xor(rm, 16));
                rm = fmaxf(rm, __shfl_xor(rm, 32));
                float mnew = fmaxf(m_i[nb], rm);
                float alpha = __builtin_amdgcn_exp2f(m_i[nb] - mnew);  // first: 0
                m_i[nb] = mnew;
#pragma unroll
                for (int db = 0; db < 5; ++db) o[db][nb] *= alpha;
            }
        }
#pragma unroll
        for (int nb = 0; nb < 2; ++nb) {
            const float m0 = m_i[nb];
#pragma unroll
            for (int mb = 0; mb < 4; ++mb) {
                f16x2 e01 = cvt_pk(__builtin_amdgcn_exp2f(s[mb][nb][0] - m0),
                                   __builtin_amdgcn_exp2f(s[mb][nb][1] - m0));
                f16x2 e23 = cvt_pk(__builtin_amdgcn_exp2f(s[mb][nb][2] - m0),
                                   __builtin_amdgcn_exp2f(s[mb][nb][3] - m0));
                pout[mb][nb] = __builtin_shufflevector(e01, e23, 0, 1, 2, 3);
            }
        }
    };

    // ---- prologue: stage 0,1; softmax(0) -> pf[0] ----
    stageK(0); stageV(0); stageK(1); stageV(1);
    asm volatile("s_waitcnt vmcnt(2)" ::: "memory");
    asm volatile("s_barrier" ::: "memory");
    {
        f32x4 s0[4][2];
        qk_step(0, s0);
        softmax_step(s0, pf[0]);
    }
    // all waves done reading Kbuf0 before iter0's stageK(2) overwrites it
    asm volatile("s_barrier" ::: "memory");

    // ---- main loop j = 0..13 (fully unrolled: static parity) ----
#pragma unroll
    for (int j = 0; j < 14; ++j) {
        stageK(j + 2);                        // Kbuf[j&1], freed by last barrier
        f32x4 s[4][2];
        qk_step(j + 1, s);                    // Kbuf[(j+1)&1]
        softmax_step(s, pf[(j + 1) & 1]);     // s dies here
        pv_step(j, pf[j & 1]);                // Vbuf[j&1]
        asm volatile("s_barrier" ::: "memory");   // all waves done w/ Vbuf[j&1]
        stageV(j + 2);                        // Vbuf[j&1]
        asm volatile("s_waitcnt vmcnt(2)" ::: "memory");
        asm volatile("s_barrier" ::: "memory");
    }
    // ---- j = 14: no further staging ----
    {
        f32x4 s[4][2];
        qk_step(15, s);
        softmax_step(s, pf[1]);
        pv_step(14, pf[0]);
        asm volatile("s_barrier" ::: "memory");
        asm volatile("s_waitcnt vmcnt(0)" ::: "memory");   // V15 lands
        asm volatile("s_barrier" ::: "memory");
    }
    // ---- epilogue: last PV ----
    pv_step(15, pf[1]);

    // extract l (held at quad==0 lanes, col c) and broadcast to the wave
    float l_i[2];
    l_i[0] = __shfl(o[4][0][0], c);
    l_i[1] = __shfl(o[4][1][0], c);

    __syncthreads();   // PV(15) LDS reads done before aliasing cO over bufs
    // ---- combine the two KV-halves via LDS, group 0 writes out ----
    if (g == 1) {
#pragma unroll
        for (int nb = 0; nb < 2; ++nb) {
            int ql = ww * 32 + nb * 16 + c;
            if (quad == 0) { cml[ql] = m_i[nb]; cml[128 + ql] = l_i[nb]; }
#pragma unroll
            for (int db = 0; db < 4; ++db) {
                int d4 = db * 4 + quad;
                *(f32x4*)&cO[(ql * 16 + (d4 ^ (ql & 15))) << 2] = o[db][nb];
            }
        }
    }
    __syncthreads();
    if (g == 0) {
#pragma unroll
        for (int nb = 0; nb < 2; ++nb) {
            int ql = ww * 32 + nb * 16 + c;
            int qq = qt * 128 + ql;
            float m2 = cml[ql], l2 = cml[128 + ql];
            float mm = fmaxf(m_i[nb], m2);
            float a1 = __builtin_amdgcn_exp2f(m_i[nb] - mm);
            float a2 = __builtin_amdgcn_exp2f(m2 - mm);
            float linv = 1.f / (l_i[nb] * a1 + l2 * a2);
#pragma unroll
            for (int db = 0; db < 4; ++db) {
                int d4 = db * 4 + quad;
                f32x4 v2 = *(const f32x4*)&cO[(ql * 16 + (d4 ^ (ql & 15))) << 2];
                f32x4 v = (o[db][nb] * a1 + v2 * a2) * linv;
                *(f32x4*)(out + ((size_t)b * S_ + qq) * H_ + hh * 64 + db * 16 + quad * 4) = v;
            }
        }
    }
}

// ---------------- launch ----------------
extern "C" void kernel_launch(void* const* d_in, const int* in_sizes, int n_in,
                              void* d_out, int out_size, void* d_ws, size_t ws_size,
                              hipStream_t stream) {
    const float* query = (const float*)d_in[0];
    const float* key   = (const float*)d_in[1];
    const float* value = (const float*)d_in[2];
    const float* mask  = (const float*)d_in[3];
    const float* Wq    = (const float*)d_in[4];
    const float* bq    = (const float*)d_in[5];
    const float* Wk    = (const float*)d_in[6];
    const float* bk    = (const float*)d_in[7];
    const float* Wv    = (const float*)d_in[8];
    const float* bv    = (const float*)d_in[9];
    float* out = (float*)d_out;

    f16* p = (f16*)d_ws;
    f16* xq = p; p += SZX; f16* xk = p; p += SZX; f16* xv = p; p += SZX;
    f16* wq = p; p += SZW; f16* wk = p; p += SZW; f16* wv = p; p += SZW;
    f16* q  = p; p += SZX; f16* k  = p; p += SZX; f16* vt = p; p += SZX;
    float* mask_s = (float*)p;   // B_*S_ floats

    const int total = 3 * (int)(SZX / 4) + 3 * (int)(SZW / 4) + (B_ * S_ / 4);
    prep_kernel<<<(total + 255) / 256, 256, 0, stream>>>(
        query, key, value, Wq, Wk, Wv, mask, xq, xk, xv, wq, wk, wv, mask_s);

    dim3 pg(24, M_ / 128);
    proj_kernel<<<pg, 256, 0, stream>>>(xq, xk, xv, wq, wk, wv, bq, bk, bv, q, k, vt);

    dim3 ag(S_ / 128, B_ * NH_);
    attn_kernel<<<ag, 512, 0, stream>>>(q, k, vt, mask_s, out);
}

// Round 12
// 198.708 us; speedup vs baseline: 2.4400x; 1.0173x over previous
//
#include <hip/hip_runtime.h>
#include <math.h>

using f16 = _Float16;
using f16x2 = __attribute__((ext_vector_type(2))) _Float16;
using f16x4 = __attribute__((ext_vector_type(4))) _Float16;
using f16x8 = __attribute__((ext_vector_type(8))) _Float16;
using f32x4 = __attribute__((ext_vector_type(4))) float;
using h16x2 = __attribute__((ext_vector_type(2))) __fp16;

static constexpr int B_ = 2, S_ = 2048, H_ = 1024, NH_ = 16, HD_ = 64;
static constexpr int M_ = B_ * S_;                 // 4096 rows of X
static constexpr size_t SZX = (size_t)M_ * H_;     // 4,194,304 elems
static constexpr size_t SZW = (size_t)H_ * H_;     // 1,048,576 elems
static constexpr float LOG2E = 1.4426950408889634f;

__device__ __forceinline__ f32x4 mfma16(f16x8 a, f16x8 b, f32x4 c) {
    return __builtin_amdgcn_mfma_f32_16x16x32_f16(a, b, c, 0, 0, 0);
}
__device__ __forceinline__ f16x2 cvt_pk(float a, float b) {
    h16x2 r = __builtin_amdgcn_cvt_pkrtz(a, b);
    return __builtin_bit_cast(f16x2, r);
}

// async 16B global -> LDS (wave-uniform LDS base + lane*16)
typedef const __attribute__((address_space(1))) unsigned int* gas_t;
typedef __attribute__((address_space(3))) unsigned int* las_t;
__device__ __forceinline__ void load16_lds(const void* g, void* lds_base) {
    __builtin_amdgcn_global_load_lds((gas_t)g, (las_t)lds_base, 16, 0, 0);
}

// ---------------- prep: fp32->fp16 x6 tensors + mask*log2e, one launch -----
// (frozen: exact kernel from the 201.8 µs run)
__global__ __launch_bounds__(256) void prep_kernel(
    const float* __restrict__ xqf, const float* __restrict__ xkf, const float* __restrict__ xvf,
    const float* __restrict__ wqf, const float* __restrict__ wkf, const float* __restrict__ wvf,
    const float* __restrict__ mask,
    f16* __restrict__ xq, f16* __restrict__ xk, f16* __restrict__ xv,
    f16* __restrict__ wq, f16* __restrict__ wk, f16* __restrict__ wv,
    float* __restrict__ mask_s) {
    constexpr int NX = (int)(SZX / 4);   // 1<<20
    constexpr int NW = (int)(SZW / 4);   // 1<<18
    static_assert(NX == (1 << 20) && NW == (1 << 18), "shift assumptions");
    int i = blockIdx.x * 256 + threadIdx.x;
    const float* src;
    f16* dst;
    int j;
    if (i < 3 * NX) {
        int z = i >> 20;
        j = i & (NX - 1);
        src = z == 0 ? xqf : z == 1 ? xkf : xvf;
        dst = z == 0 ? xq : z == 1 ? xk : xv;
    } else if (i < 3 * NX + 3 * NW) {
        int r = i - 3 * NX;
        int z = r >> 18;
        j = r & (NW - 1);
        src = z == 0 ? wqf : z == 1 ? wkf : wvf;
        dst = z == 0 ? wq : z == 1 ? wk : wv;
    } else {
        int r = i - (3 * NX + 3 * NW);
        if (r < B_ * S_ / 4) {
            f32x4 m = ((const f32x4*)mask)[r];
            ((f32x4*)mask_s)[r] = m * LOG2E;
        }
        return;
    }
    f32x4 v = ((const f32x4*)src)[j];
    f16x4 h;
#pragma unroll
    for (int r = 0; r < 4; ++r) h[r] = (f16)v[r];
    ((f16x4*)dst)[j] = h;
}

// ---------------- merged Q/K/V projection + XCD-chunked remap --------------
// ONLY change vs the 202 µs run: 1D grid 768 with bijective XCD chunking
// o=(lid%8)*96+lid/8 (768=8x96). XCD i gets o in [96i,96i+96): one tensor
// (mostly), ~12 consecutive row-panels (3MB X-slice) x all 8 col-blocks
// (2MB W) ~= 5MB ~= L2 -> X/W re-reads become L2 hits (proj was
// latency-bound on L3 trips with zero inter-block sharing, r9 counters).
__global__ __launch_bounds__(256, 2) void proj_kernel(
    const f16* __restrict__ xq, const f16* __restrict__ xk, const f16* __restrict__ xv,
    const f16* __restrict__ wq, const f16* __restrict__ wk, const f16* __restrict__ wv,
    const float* __restrict__ bq, const float* __restrict__ bk, const float* __restrict__ bv,
    f16* __restrict__ q, f16* __restrict__ k, f16* __restrict__ vt) {
    __shared__ alignas(16) f16 sX[128][64];
    __shared__ alignas(16) f16 sW[128][64];
    const int t = threadIdx.x, w = t >> 6, lane = t & 63, c = lane & 15, quad = lane >> 4;
    const int lid = blockIdx.x;
    const int o = (lid & 7) * 96 + (lid >> 3);     // bijective XCD chunking
    const int which = o >> 8;
    const int row0 = ((o >> 3) & 31) * 128;
    const int col0 = (o & 7) * 128;
    const f16* X = which == 0 ? xq : which == 1 ? xk : xv;
    const f16* W = which == 0 ? wq : which == 1 ? wk : wv;
    const int wm = (w & 1) * 64, wn = (w >> 1) * 64;
    f32x4 acc[4][4] = {};

    for (int k0 = 0; k0 < H_; k0 += 64) {
        if (k0) __syncthreads();
#pragma unroll
        for (int i = 0; i < 4; ++i) {
            int r = 8 * w + 32 * i + (lane >> 3);
            int cb = (lane & 7) ^ ((lane >> 3) & 7);
            load16_lds(X + (size_t)(row0 + r) * H_ + k0 + cb * 8, &sX[8 * w + 32 * i][0]);
            load16_lds(W + (size_t)(col0 + r) * H_ + k0 + cb * 8, &sW[8 * w + 32 * i][0]);
        }
        __syncthreads();
        if (which == 2) {
#pragma unroll
            for (int ks = 0; ks < 2; ++ks) {
                const int ph = ((ks * 4 + quad) ^ (c & 7)) * 8;
                f16x8 wf[4], xf[4];
#pragma unroll
                for (int gg = 0; gg < 4; ++gg) {
                    wf[gg] = *(const f16x8*)&sW[wn + gg * 16 + c][ph];
                    xf[gg] = *(const f16x8*)&sX[wm + gg * 16 + c][ph];
                }
#pragma unroll
                for (int mg = 0; mg < 4; ++mg)
#pragma unroll
                    for (int ng = 0; ng < 4; ++ng)
                        acc[mg][ng] = mfma16(xf[mg], wf[ng], acc[mg][ng]);
            }
        } else {
#pragma unroll
            for (int ks = 0; ks < 2; ++ks) {
                const int ph = ((ks * 4 + quad) ^ (c & 7)) * 8;
                f16x8 wf[4], xf[4];
#pragma unroll
                for (int gg = 0; gg < 4; ++gg) {
                    wf[gg] = *(const f16x8*)&sW[wn + gg * 16 + c][ph];
                    xf[gg] = *(const f16x8*)&sX[wm + gg * 16 + c][ph];
                }
#pragma unroll
                for (int mg = 0; mg < 4; ++mg)
#pragma unroll
                    for (int ng = 0; ng < 4; ++ng)
                        acc[mg][ng] = mfma16(wf[ng], xf[mg], acc[mg][ng]);
            }
        }
    }

    if (which < 2) {
        const float* bias = which ? bk : bq;
        f16* O = which ? k : q;
        const float scale = which ? 1.0f : (LOG2E * 0.125f);
#pragma unroll
        for (int ng = 0; ng < 4; ++ng) {
            int col4 = col0 + wn + ng * 16 + quad * 4;
            f32x4 bv_ = *(const f32x4*)(bias + col4);
            int hh = col4 >> 6, d = col4 & 63;
#pragma unroll
            for (int mg = 0; mg < 4; ++mg) {
                int rowg = row0 + wm + mg * 16 + c;
                int bb = rowg >> 11, ss = rowg & (S_ - 1);
                f16x4 ov;
#pragma unroll
                for (int r = 0; r < 4; ++r) ov[r] = (f16)((acc[mg][ng][r] + bv_[r]) * scale);
                *(f16x4*)(O + ((size_t)(bb * NH_ + hh) * S_ + ss) * HD_ + d) = ov;
            }
        }
    } else {
#pragma unroll
        for (int ng = 0; ng < 4; ++ng) {
            int col = col0 + wn + ng * 16 + c;
            float bv_ = bv[col];
            int hh = col >> 6, d = col & 63;
#pragma unroll
            for (int mg = 0; mg < 4; ++mg) {
                int rbase = row0 + wm + mg * 16 + quad * 4;
                int bb = rbase >> 11, ss = rbase & (S_ - 1);
                int sl = ss & 31;   // 4-aligned: k1k0 = 0
                int pp = (ss & ~31) | (((sl >> 4) & 1) << 2) | (((sl >> 2) & 1) << 3) | (((sl >> 3) & 1) << 4);
                f16x4 ov;
#pragma unroll
                for (int r = 0; r < 4; ++r) ov[r] = (f16)(acc[mg][ng][r] + bv_);
                *(f16x4*)(vt + ((size_t)(bb * NH_ + hh) * HD_ + d) * S_ + pp) = ov;
            }
        }
    }
}

// ---------------- flash attention, split-KV, s-dies-early pipeline ----------
// (frozen: exact kernel from the r7/r11 runs)
__global__ __launch_bounds__(512, 2) void attn_kernel(
    const f16* __restrict__ Q, const f16* __restrict__ K,
    const f16* __restrict__ VT, const float* __restrict__ mask_s,
    float* __restrict__ out) {
    __shared__ alignas(128) unsigned char smem[74752];

    const int t = threadIdx.x, w = t >> 6, lane = t & 63, c = lane & 15, quad = lane >> 4;
    const int g = w >> 2, ww = w & 3;
    const int qt = blockIdx.x, bh = blockIdx.y;
    const int b = bh >> 4, hh = bh & 15;
    const size_t qkb = (size_t)bh * S_ * HD_;
    const size_t vtb = (size_t)bh * HD_ * S_;

    unsigned char* gmem = smem + g * 36864;
    float* maskL = (float*)(gmem + 32768);
    float* cml = (float*)(smem + 73728);
    float* cO = (float*)smem;

    // Q fragments (registers, whole K-loop)
    f16x8 qf[2][2];
#pragma unroll
    for (int nb = 0; nb < 2; ++nb)
#pragma unroll
        for (int ch = 0; ch < 2; ++ch) {
            int qq = qt * 128 + ww * 32 + nb * 16 + c;
            qf[nb][ch] = *(const f16x8*)(Q + qkb + (size_t)qq * HD_ + ch * 32 + quad * 8);
        }

    const int lr = lane >> 3;                  // 0..7
    const int lcb = (lane & 7) ^ lr;           // XOR-swizzled col-block
    const f16* kbase = K + qkb + (size_t)(8 * ww + lr) * HD_ + lcb * 8;
    const f16* vtbase = VT + vtb + (size_t)(8 * ww + lr) * S_ + lcb * 8;

    // stage this group's mask half (prescaled f32) into LDS, once
    load16_lds(mask_s + b * S_ + g * 1024 + ww * 256, gmem + 32768 + ww * 1024);

    auto stageK = [&](int j) {     // K tile j -> Kbuf[j&1]  (2 loads)
        const int kt2 = g * 16 + j;
        f16* dK = (f16*)(gmem + (j & 1) * 8192) + 8 * ww * 64;
        load16_lds(kbase + (size_t)(kt2 * 64) * HD_, dK);
        load16_lds(kbase + (size_t)(kt2 * 64 + 32) * HD_, dK + 32 * 64);
    };
    auto stageV = [&](int j) {     // V tile j -> Vbuf[j&1]  (2 loads)
        const int kt2 = g * 16 + j;
        f16* dV = (f16*)(gmem + 16384 + (j & 1) * 8192) + 8 * ww * 64;
        load16_lds(vtbase + kt2 * 64, dV);
        load16_lds(vtbase + (size_t)32 * S_ + kt2 * 64, dV + 32 * 64);
    };

    // ones-row A fragment for the l accumulator (row d=64 of virtual V^T)
    const f16 one_ = (c == 0) ? (f16)1 : (f16)0;
    const f16x8 af_ones = {one_, one_, one_, one_, one_, one_, one_, one_};

    f32x4 o[5][2] = {};   // db=4 row holds l at (quad==0, elem 0)
    float m_i[2] = {-INFINITY, -INFINITY};
    f16x4 pf[2][4][2];    // static double-buffered P (parity-indexed)

    auto qk_step = [&](int j, f32x4(&s)[4][2]) {   // S^T(tile j) = mask + K·Q^T
        const f16(*sKc)[64] = (const f16(*)[64])(gmem + (j & 1) * 8192);
#pragma unroll
        for (int mb = 0; mb < 4; ++mb) {
            f32x4 mv = *(const f32x4*)(maskL + j * 64 + mb * 16 + quad * 4);
            s[mb][0] = mv;
            s[mb][1] = mv;
        }
#pragma unroll
        for (int ch = 0; ch < 2; ++ch) {
            const int ph = ((ch * 4 + quad) ^ (c & 7)) * 8;
#pragma unroll
            for (int mb = 0; mb < 4; ++mb) {
                f16x8 ah = *(const f16x8*)&sKc[mb * 16 + c][ph];
                s[mb][0] = mfma16(ah, qf[0][ch], s[mb][0]);
                s[mb][1] = mfma16(ah, qf[1][ch], s[mb][1]);
            }
        }
    };
    auto pv_step = [&](int j, f16x4(&pin)[4][2]) { // O^T += V^T(tile j)·P^T
        const f16(*sVc)[64] = (const f16(*)[64])(gmem + 16384 + (j & 1) * 8192);
#pragma unroll
        for (int kcc = 0; kcc < 2; ++kcc) {
            const int blk = kcc * 4 + quad;
            const int pblk = (blk ^ c) & 7;
            f16x8 bf0 = __builtin_shufflevector(pin[2 * kcc][0], pin[2 * kcc + 1][0],
                                                0, 1, 2, 3, 4, 5, 6, 7);
            f16x8 bf1 = __builtin_shufflevector(pin[2 * kcc][1], pin[2 * kcc + 1][1],
                                                0, 1, 2, 3, 4, 5, 6, 7);
#pragma unroll
            for (int db = 0; db < 5; ++db) {
                f16x8 af = (db == 4) ? af_ones : *(const f16x8*)&sVc[db * 16 + c][pblk * 8];
                o[db][0] = mfma16(af, bf0, o[db][0]);
                o[db][1] = mfma16(af, bf1, o[db][1]);
            }
        }
    };
    auto softmax_step = [&](f32x4(&s)[4][2], f16x4(&pout)[4][2]) {
        float rloc[2];
#pragma unroll
        for (int nb = 0; nb < 2; ++nb) {
            float a0 = fmaxf(fmaxf(s[0][nb][0], s[0][nb][1]), s[0][nb][2]);
            float a1 = fmaxf(fmaxf(s[0][nb][3], s[1][nb][0]), s[1][nb][1]);
            float a2 = fmaxf(fmaxf(s[1][nb][2], s[1][nb][3]), s[2][nb][0]);
            float a3 = fmaxf(fmaxf(s[2][nb][1], s[2][nb][2]), s[2][nb][3]);
            float a4 = fmaxf(fmaxf(s[3][nb][0], s[3][nb][1]), s[3][nb][2]);
            float b0 = fmaxf(fmaxf(a0, a1), a2);
            float b1 = fmaxf(fmaxf(a3, a4), s[3][nb][3]);
            rloc[nb] = fmaxf(b0, b1);
        }
        if (__any(rloc[0] > m_i[0] + 8.f || rloc[1] > m_i[1] + 8.f)) {
#pragma unroll
            for (int nb = 0; nb < 2; ++nb) {
                float rm = rloc[nb];
                rm = fmaxf(rm, __shfl_xor(rm, 16));
                rm = fmaxf(rm, __shfl_xor(rm, 32));
                float mnew = fmaxf(m_i[nb], rm);
                float alpha = __builtin_amdgcn_exp2f(m_i[nb] - mnew);  // first: 0
                m_i[nb] = mnew;
#pragma unroll
                for (int db = 0; db < 5; ++db) o[db][nb] *= alpha;
            }
        }
#pragma unroll
        for (int nb = 0; nb < 2; ++nb) {
            const float m0 = m_i[nb];
#pragma unroll
            for (int mb = 0; mb < 4; ++mb) {
                f16x2 e01 = cvt_pk(__builtin_amdgcn_exp2f(s[mb][nb][0] - m0),
                                   __builtin_amdgcn_exp2f(s[mb][nb][1] - m0));
                f16x2 e23 = cvt_pk(__builtin_amdgcn_exp2f(s[mb][nb][2] - m0),
                                   __builtin_amdgcn_exp2f(s[mb][nb][3] - m0));
                pout[mb][nb] = __builtin_shufflevector(e01, e23, 0, 1, 2, 3);
            }
        }
    };

    // ---- prologue: stage 0,1; softmax(0) -> pf[0] ----
    stageK(0); stageV(0); stageK(1); stageV(1);
    asm volatile("s_waitcnt vmcnt(2)" ::: "memory");
    asm volatile("s_barrier" ::: "memory");
    {
        f32x4 s0[4][2];
        qk_step(0, s0);
        softmax_step(s0, pf[0]);
    }
    // all waves done reading Kbuf0 before iter0's stageK(2) overwrites it
    asm volatile("s_barrier" ::: "memory");

    // ---- main loop j = 0..13 (fully unrolled: static parity) ----
#pragma unroll
    for (int j = 0; j < 14; ++j) {
        stageK(j + 2);                        // Kbuf[j&1], freed by last barrier
        f32x4 s[4][2];
        qk_step(j + 1, s);                    // Kbuf[(j+1)&1]
        softmax_step(s, pf[(j + 1) & 1]);     // s dies here
        pv_step(j, pf[j & 1]);                // Vbuf[j&1]
        asm volatile("s_barrier" ::: "memory");   // all waves done w/ Vbuf[j&1]
        stageV(j + 2);                        // Vbuf[j&1]
        asm volatile("s_waitcnt vmcnt(2)" ::: "memory");
        asm volatile("s_barrier" ::: "memory");
    }
    // ---- j = 14: no further staging ----
    {
        f32x4 s[4][2];
        qk_step(15, s);
        softmax_step(s, pf[1]);
        pv_step(14, pf[0]);
        asm volatile("s_barrier" ::: "memory");
        asm volatile("s_waitcnt vmcnt(0)" ::: "memory");   // V15 lands
        asm volatile("s_barrier" ::: "memory");
    }
    // ---- epilogue: last PV ----
    pv_step(15, pf[1]);

    // extract l (held at quad==0 lanes, col c) and broadcast to the wave
    float l_i[2];
    l_i[0] = __shfl(o[4][0][0], c);
    l_i[1] = __shfl(o[4][1][0], c);

    __syncthreads();   // PV(15) LDS reads done before aliasing cO over bufs
    // ---- combine the two KV-halves via LDS, group 0 writes out ----
    if (g == 1) {
#pragma unroll
        for (int nb = 0; nb < 2; ++nb) {
            int ql = ww * 32 + nb * 16 + c;
            if (quad == 0) { cml[ql] = m_i[nb]; cml[128 + ql] = l_i[nb]; }
#pragma unroll
            for (int db = 0; db < 4; ++db) {
                int d4 = db * 4 + quad;
                *(f32x4*)&cO[(ql * 16 + (d4 ^ (ql & 15))) << 2] = o[db][nb];
            }
        }
    }
    __syncthreads();
    if (g == 0) {
#pragma unroll
        for (int nb = 0; nb < 2; ++nb) {
            int ql = ww * 32 + nb * 16 + c;
            int qq = qt * 128 + ql;
            float m2 = cml[ql], l2 = cml[128 + ql];
            float mm = fmaxf(m_i[nb], m2);
            float a1 = __builtin_amdgcn_exp2f(m_i[nb] - mm);
            float a2 = __builtin_amdgcn_exp2f(m2 - mm);
            float linv = 1.f / (l_i[nb] * a1 + l2 * a2);
#pragma unroll
            for (int db = 0; db < 4; ++db) {
                int d4 = db * 4 + quad;
                f32x4 v2 = *(const f32x4*)&cO[(ql * 16 + (d4 ^ (ql & 15))) << 2];
                f32x4 v = (o[db][nb] * a1 + v2 * a2) * linv;
                *(f32x4*)(out + ((size_t)b * S_ + qq) * H_ + hh * 64 + db * 16 + quad * 4) = v;
            }
        }
    }
}

// ---------------- launch ----------------
extern "C" void kernel_launch(void* const* d_in, const int* in_sizes, int n_in,
                              void* d_out, int out_size, void* d_ws, size_t ws_size,
                              hipStream_t stream) {
    const float* query = (const float*)d_in[0];
    const float* key   = (const float*)d_in[1];
    const float* value = (const float*)d_in[2];
    const float* mask  = (const float*)d_in[3];
    const float* Wq    = (const float*)d_in[4];
    const float* bq    = (const float*)d_in[5];
    const float* Wk    = (const float*)d_in[6];
    const float* bk    = (const float*)d_in[7];
    const float* Wv    = (const float*)d_in[8];
    const float* bv    = (const float*)d_in[9];
    float* out = (float*)d_out;

    f16* p = (f16*)d_ws;
    f16* xq = p; p += SZX; f16* xk = p; p += SZX; f16* xv = p; p += SZX;
    f16* wq = p; p += SZW; f16* wk = p; p += SZW; f16* wv = p; p += SZW;
    f16* q  = p; p += SZX; f16* k  = p; p += SZX; f16* vt = p; p += SZX;
    float* mask_s = (float*)p;   // B_*S_ floats

    const int total = 3 * (int)(SZX / 4) + 3 * (int)(SZW / 4) + (B_ * S_ / 4);
    prep_kernel<<<(total + 255) / 256, 256, 0, stream>>>(
        query, key, value, Wq, Wk, Wv, mask, xq, xk, xv, wq, wk, wv, mask_s);

    proj_kernel<<<768, 256, 0, stream>>>(xq, xk, xv, wq, wk, wv, bq, bk, bv, q, k, vt);

    dim3 ag(S_ / 128, B_ * NH_);
    attn_kernel<<<ag, 512, 0, stream>>>(q, k, vt, mask_s, out);
}

// Round 13
// 198.268 us; speedup vs baseline: 2.4454x; 1.0022x over previous
//
#include <hip/hip_runtime.h>
#include <math.h>

using f16 = _Float16;
using f16x2 = __attribute__((ext_vector_type(2))) _Float16;
using f16x4 = __attribute__((ext_vector_type(4))) _Float16;
using f16x8 = __attribute__((ext_vector_type(8))) _Float16;
using f32x4 = __attribute__((ext_vector_type(4))) float;
using h16x2 = __attribute__((ext_vector_type(2))) __fp16;

static constexpr int B_ = 2, S_ = 2048, H_ = 1024, NH_ = 16, HD_ = 64;
static constexpr int M_ = B_ * S_;                 // 4096 rows of X
static constexpr size_t SZX = (size_t)M_ * H_;     // 4,194,304 elems
static constexpr size_t SZW = (size_t)H_ * H_;     // 1,048,576 elems
static constexpr float LOG2E = 1.4426950408889634f;

__device__ __forceinline__ f32x4 mfma16(f16x8 a, f16x8 b, f32x4 c) {
    return __builtin_amdgcn_mfma_f32_16x16x32_f16(a, b, c, 0, 0, 0);
}
__device__ __forceinline__ f16x2 cvt_pk(float a, float b) {
    h16x2 r = __builtin_amdgcn_cvt_pkrtz(a, b);
    return __builtin_bit_cast(f16x2, r);
}

// async 16B global -> LDS (wave-uniform LDS base + lane*16)
typedef const __attribute__((address_space(1))) unsigned int* gas_t;
typedef __attribute__((address_space(3))) unsigned int* las_t;
__device__ __forceinline__ void load16_lds(const void* g, void* lds_base) {
    __builtin_amdgcn_global_load_lds((gas_t)g, (las_t)lds_base, 16, 0, 0);
}

// ---------------- prep: fp32->fp16 x6 tensors + mask*log2e, one launch -----
// (frozen)
__global__ __launch_bounds__(256) void prep_kernel(
    const float* __restrict__ xqf, const float* __restrict__ xkf, const float* __restrict__ xvf,
    const float* __restrict__ wqf, const float* __restrict__ wkf, const float* __restrict__ wvf,
    const float* __restrict__ mask,
    f16* __restrict__ xq, f16* __restrict__ xk, f16* __restrict__ xv,
    f16* __restrict__ wq, f16* __restrict__ wk, f16* __restrict__ wv,
    float* __restrict__ mask_s) {
    constexpr int NX = (int)(SZX / 4);   // 1<<20
    constexpr int NW = (int)(SZW / 4);   // 1<<18
    static_assert(NX == (1 << 20) && NW == (1 << 18), "shift assumptions");
    int i = blockIdx.x * 256 + threadIdx.x;
    const float* src;
    f16* dst;
    int j;
    if (i < 3 * NX) {
        int z = i >> 20;
        j = i & (NX - 1);
        src = z == 0 ? xqf : z == 1 ? xkf : xvf;
        dst = z == 0 ? xq : z == 1 ? xk : xv;
    } else if (i < 3 * NX + 3 * NW) {
        int r = i - 3 * NX;
        int z = r >> 18;
        j = r & (NW - 1);
        src = z == 0 ? wqf : z == 1 ? wkf : wvf;
        dst = z == 0 ? wq : z == 1 ? wk : wv;
    } else {
        int r = i - (3 * NX + 3 * NW);
        if (r < B_ * S_ / 4) {
            f32x4 m = ((const f32x4*)mask)[r];
            ((f32x4*)mask_s)[r] = m * LOG2E;
        }
        return;
    }
    f32x4 v = ((const f32x4*)src)[j];
    f16x4 h;
#pragma unroll
    for (int r = 0; r < 4; ++r) h[r] = (f16)v[r];
    ((f16x4*)dst)[j] = h;
}

// ---------------- merged Q/K/V projection + XCD-chunked remap --------------
// (frozen: exact kernel from the 198.7 µs run)
__global__ __launch_bounds__(256, 2) void proj_kernel(
    const f16* __restrict__ xq, const f16* __restrict__ xk, const f16* __restrict__ xv,
    const f16* __restrict__ wq, const f16* __restrict__ wk, const f16* __restrict__ wv,
    const float* __restrict__ bq, const float* __restrict__ bk, const float* __restrict__ bv,
    f16* __restrict__ q, f16* __restrict__ k, f16* __restrict__ vt) {
    __shared__ alignas(16) f16 sX[128][64];
    __shared__ alignas(16) f16 sW[128][64];
    const int t = threadIdx.x, w = t >> 6, lane = t & 63, c = lane & 15, quad = lane >> 4;
    const int lid = blockIdx.x;
    const int o = (lid & 7) * 96 + (lid >> 3);     // bijective XCD chunking
    const int which = o >> 8;
    const int row0 = ((o >> 3) & 31) * 128;
    const int col0 = (o & 7) * 128;
    const f16* X = which == 0 ? xq : which == 1 ? xk : xv;
    const f16* W = which == 0 ? wq : which == 1 ? wk : wv;
    const int wm = (w & 1) * 64, wn = (w >> 1) * 64;
    f32x4 acc[4][4] = {};

    for (int k0 = 0; k0 < H_; k0 += 64) {
        if (k0) __syncthreads();
#pragma unroll
        for (int i = 0; i < 4; ++i) {
            int r = 8 * w + 32 * i + (lane >> 3);
            int cb = (lane & 7) ^ ((lane >> 3) & 7);
            load16_lds(X + (size_t)(row0 + r) * H_ + k0 + cb * 8, &sX[8 * w + 32 * i][0]);
            load16_lds(W + (size_t)(col0 + r) * H_ + k0 + cb * 8, &sW[8 * w + 32 * i][0]);
        }
        __syncthreads();
        if (which == 2) {
#pragma unroll
            for (int ks = 0; ks < 2; ++ks) {
                const int ph = ((ks * 4 + quad) ^ (c & 7)) * 8;
                f16x8 wf[4], xf[4];
#pragma unroll
                for (int gg = 0; gg < 4; ++gg) {
                    wf[gg] = *(const f16x8*)&sW[wn + gg * 16 + c][ph];
                    xf[gg] = *(const f16x8*)&sX[wm + gg * 16 + c][ph];
                }
#pragma unroll
                for (int mg = 0; mg < 4; ++mg)
#pragma unroll
                    for (int ng = 0; ng < 4; ++ng)
                        acc[mg][ng] = mfma16(xf[mg], wf[ng], acc[mg][ng]);
            }
        } else {
#pragma unroll
            for (int ks = 0; ks < 2; ++ks) {
                const int ph = ((ks * 4 + quad) ^ (c & 7)) * 8;
                f16x8 wf[4], xf[4];
#pragma unroll
                for (int gg = 0; gg < 4; ++gg) {
                    wf[gg] = *(const f16x8*)&sW[wn + gg * 16 + c][ph];
                    xf[gg] = *(const f16x8*)&sX[wm + gg * 16 + c][ph];
                }
#pragma unroll
                for (int mg = 0; mg < 4; ++mg)
#pragma unroll
                    for (int ng = 0; ng < 4; ++ng)
                        acc[mg][ng] = mfma16(wf[ng], xf[mg], acc[mg][ng]);
            }
        }
    }

    if (which < 2) {
        const float* bias = which ? bk : bq;
        f16* O = which ? k : q;
        const float scale = which ? 1.0f : (LOG2E * 0.125f);
#pragma unroll
        for (int ng = 0; ng < 4; ++ng) {
            int col4 = col0 + wn + ng * 16 + quad * 4;
            f32x4 bv_ = *(const f32x4*)(bias + col4);
            int hh = col4 >> 6, d = col4 & 63;
#pragma unroll
            for (int mg = 0; mg < 4; ++mg) {
                int rowg = row0 + wm + mg * 16 + c;
                int bb = rowg >> 11, ss = rowg & (S_ - 1);
                f16x4 ov;
#pragma unroll
                for (int r = 0; r < 4; ++r) ov[r] = (f16)((acc[mg][ng][r] + bv_[r]) * scale);
                *(f16x4*)(O + ((size_t)(bb * NH_ + hh) * S_ + ss) * HD_ + d) = ov;
            }
        }
    } else {
#pragma unroll
        for (int ng = 0; ng < 4; ++ng) {
            int col = col0 + wn + ng * 16 + c;
            float bv_ = bv[col];
            int hh = col >> 6, d = col & 63;
#pragma unroll
            for (int mg = 0; mg < 4; ++mg) {
                int rbase = row0 + wm + mg * 16 + quad * 4;
                int bb = rbase >> 11, ss = rbase & (S_ - 1);
                int sl = ss & 31;   // 4-aligned: k1k0 = 0
                int pp = (ss & ~31) | (((sl >> 4) & 1) << 2) | (((sl >> 2) & 1) << 3) | (((sl >> 3) & 1) << 4);
                f16x4 ov;
#pragma unroll
                for (int r = 0; r < 4; ++r) ov[r] = (f16)(acc[mg][ng][r] + bv_);
                *(f16x4*)(vt + ((size_t)(bb * NH_ + hh) * HD_ + d) * S_ + pp) = ov;
            }
        }
    }
}

// ---------------- flash attention, split-KV, s-dies-early pipeline ----------
// ONLY change vs the 198.7 run: 1D grid 512 with bijective XCD chunking
// o=(lid%8)*64+lid/8 (512=8x64). XCD i gets o in [64i,64i+64): 4 consecutive
// heads x all 16 q-tiles -> the 16 blocks sharing one head's K/V (512KB) are
// co-resident on ONE XCD; K/V slice 2MB fits L2 -> re-fetch becomes L2 hits
// (attn FETCH 69.9MB vs 42MB ideal = ~28MB K/V re-fetch under round-robin).
__global__ __launch_bounds__(512, 2) void attn_kernel(
    const f16* __restrict__ Q, const f16* __restrict__ K,
    const f16* __restrict__ VT, const float* __restrict__ mask_s,
    float* __restrict__ out) {
    __shared__ alignas(128) unsigned char smem[74752];

    const int t = threadIdx.x, w = t >> 6, lane = t & 63, c = lane & 15, quad = lane >> 4;
    const int g = w >> 2, ww = w & 3;
    const int lid = blockIdx.x;
    const int o_ = (lid & 7) * 64 + (lid >> 3);    // bijective XCD chunking
    const int qt = o_ & 15, bh = o_ >> 4;
    const int b = bh >> 4, hh = bh & 15;
    const size_t qkb = (size_t)bh * S_ * HD_;
    const size_t vtb = (size_t)bh * HD_ * S_;

    unsigned char* gmem = smem + g * 36864;
    float* maskL = (float*)(gmem + 32768);
    float* cml = (float*)(smem + 73728);
    float* cO = (float*)smem;

    // Q fragments (registers, whole K-loop)
    f16x8 qf[2][2];
#pragma unroll
    for (int nb = 0; nb < 2; ++nb)
#pragma unroll
        for (int ch = 0; ch < 2; ++ch) {
            int qq = qt * 128 + ww * 32 + nb * 16 + c;
            qf[nb][ch] = *(const f16x8*)(Q + qkb + (size_t)qq * HD_ + ch * 32 + quad * 8);
        }

    const int lr = lane >> 3;                  // 0..7
    const int lcb = (lane & 7) ^ lr;           // XOR-swizzled col-block
    const f16* kbase = K + qkb + (size_t)(8 * ww + lr) * HD_ + lcb * 8;
    const f16* vtbase = VT + vtb + (size_t)(8 * ww + lr) * S_ + lcb * 8;

    // stage this group's mask half (prescaled f32) into LDS, once
    load16_lds(mask_s + b * S_ + g * 1024 + ww * 256, gmem + 32768 + ww * 1024);

    auto stageK = [&](int j) {     // K tile j -> Kbuf[j&1]  (2 loads)
        const int kt2 = g * 16 + j;
        f16* dK = (f16*)(gmem + (j & 1) * 8192) + 8 * ww * 64;
        load16_lds(kbase + (size_t)(kt2 * 64) * HD_, dK);
        load16_lds(kbase + (size_t)(kt2 * 64 + 32) * HD_, dK + 32 * 64);
    };
    auto stageV = [&](int j) {     // V tile j -> Vbuf[j&1]  (2 loads)
        const int kt2 = g * 16 + j;
        f16* dV = (f16*)(gmem + 16384 + (j & 1) * 8192) + 8 * ww * 64;
        load16_lds(vtbase + kt2 * 64, dV);
        load16_lds(vtbase + (size_t)32 * S_ + kt2 * 64, dV + 32 * 64);
    };

    // ones-row A fragment for the l accumulator (row d=64 of virtual V^T)
    const f16 one_ = (c == 0) ? (f16)1 : (f16)0;
    const f16x8 af_ones = {one_, one_, one_, one_, one_, one_, one_, one_};

    f32x4 o[5][2] = {};   // db=4 row holds l at (quad==0, elem 0)
    float m_i[2] = {-INFINITY, -INFINITY};
    f16x4 pf[2][4][2];    // static double-buffered P (parity-indexed)

    auto qk_step = [&](int j, f32x4(&s)[4][2]) {   // S^T(tile j) = mask + K·Q^T
        const f16(*sKc)[64] = (const f16(*)[64])(gmem + (j & 1) * 8192);
#pragma unroll
        for (int mb = 0; mb < 4; ++mb) {
            f32x4 mv = *(const f32x4*)(maskL + j * 64 + mb * 16 + quad * 4);
            s[mb][0] = mv;
            s[mb][1] = mv;
        }
#pragma unroll
        for (int ch = 0; ch < 2; ++ch) {
            const int ph = ((ch * 4 + quad) ^ (c & 7)) * 8;
#pragma unroll
            for (int mb = 0; mb < 4; ++mb) {
                f16x8 ah = *(const f16x8*)&sKc[mb * 16 + c][ph];
                s[mb][0] = mfma16(ah, qf[0][ch], s[mb][0]);
                s[mb][1] = mfma16(ah, qf[1][ch], s[mb][1]);
            }
        }
    };
    auto pv_step = [&](int j, f16x4(&pin)[4][2]) { // O^T += V^T(tile j)·P^T
        const f16(*sVc)[64] = (const f16(*)[64])(gmem + 16384 + (j & 1) * 8192);
#pragma unroll
        for (int kcc = 0; kcc < 2; ++kcc) {
            const int blk = kcc * 4 + quad;
            const int pblk = (blk ^ c) & 7;
            f16x8 bf0 = __builtin_shufflevector(pin[2 * kcc][0], pin[2 * kcc + 1][0],
                                                0, 1, 2, 3, 4, 5, 6, 7);
            f16x8 bf1 = __builtin_shufflevector(pin[2 * kcc][1], pin[2 * kcc + 1][1],
                                                0, 1, 2, 3, 4, 5, 6, 7);
#pragma unroll
            for (int db = 0; db < 5; ++db) {
                f16x8 af = (db == 4) ? af_ones : *(const f16x8*)&sVc[db * 16 + c][pblk * 8];
                o[db][0] = mfma16(af, bf0, o[db][0]);
                o[db][1] = mfma16(af, bf1, o[db][1]);
            }
        }
    };
    auto softmax_step = [&](f32x4(&s)[4][2], f16x4(&pout)[4][2]) {
        float rloc[2];
#pragma unroll
        for (int nb = 0; nb < 2; ++nb) {
            float a0 = fmaxf(fmaxf(s[0][nb][0], s[0][nb][1]), s[0][nb][2]);
            float a1 = fmaxf(fmaxf(s[0][nb][3], s[1][nb][0]), s[1][nb][1]);
            float a2 = fmaxf(fmaxf(s[1][nb][2], s[1][nb][3]), s[2][nb][0]);
            float a3 = fmaxf(fmaxf(s[2][nb][1], s[2][nb][2]), s[2][nb][3]);
            float a4 = fmaxf(fmaxf(s[3][nb][0], s[3][nb][1]), s[3][nb][2]);
            float b0 = fmaxf(fmaxf(a0, a1), a2);
            float b1 = fmaxf(fmaxf(a3, a4), s[3][nb][3]);
            rloc[nb] = fmaxf(b0, b1);
        }
        if (__any(rloc[0] > m_i[0] + 8.f || rloc[1] > m_i[1] + 8.f)) {
#pragma unroll
            for (int nb = 0; nb < 2; ++nb) {
                float rm = rloc[nb];
                rm = fmaxf(rm, __shfl_xor(rm, 16));
                rm = fmaxf(rm, __shfl_xor(rm, 32));
                float mnew = fmaxf(m_i[nb], rm);
                float alpha = __builtin_amdgcn_exp2f(m_i[nb] - mnew);  // first: 0
                m_i[nb] = mnew;
#pragma unroll
                for (int db = 0; db < 5; ++db) o[db][nb] *= alpha;
            }
        }
#pragma unroll
        for (int nb = 0; nb < 2; ++nb) {
            const float m0 = m_i[nb];
#pragma unroll
            for (int mb = 0; mb < 4; ++mb) {
                f16x2 e01 = cvt_pk(__builtin_amdgcn_exp2f(s[mb][nb][0] - m0),
                                   __builtin_amdgcn_exp2f(s[mb][nb][1] - m0));
                f16x2 e23 = cvt_pk(__builtin_amdgcn_exp2f(s[mb][nb][2] - m0),
                                   __builtin_amdgcn_exp2f(s[mb][nb][3] - m0));
                pout[mb][nb] = __builtin_shufflevector(e01, e23, 0, 1, 2, 3);
            }
        }
    };

    // ---- prologue: stage 0,1; softmax(0) -> pf[0] ----
    stageK(0); stageV(0); stageK(1); stageV(1);
    asm volatile("s_waitcnt vmcnt(2)" ::: "memory");
    asm volatile("s_barrier" ::: "memory");
    {
        f32x4 s0[4][2];
        qk_step(0, s0);
        softmax_step(s0, pf[0]);
    }
    // all waves done reading Kbuf0 before iter0's stageK(2) overwrites it
    asm volatile("s_barrier" ::: "memory");

    // ---- main loop j = 0..13 (fully unrolled: static parity) ----
#pragma unroll
    for (int j = 0; j < 14; ++j) {
        stageK(j + 2);                        // Kbuf[j&1], freed by last barrier
        f32x4 s[4][2];
        qk_step(j + 1, s);                    // Kbuf[(j+1)&1]
        softmax_step(s, pf[(j + 1) & 1]);     // s dies here
        pv_step(j, pf[j & 1]);                // Vbuf[j&1]
        asm volatile("s_barrier" ::: "memory");   // all waves done w/ Vbuf[j&1]
        stageV(j + 2);                        // Vbuf[j&1]
        asm volatile("s_waitcnt vmcnt(2)" ::: "memory");
        asm volatile("s_barrier" ::: "memory");
    }
    // ---- j = 14: no further staging ----
    {
        f32x4 s[4][2];
        qk_step(15, s);
        softmax_step(s, pf[1]);
        pv_step(14, pf[0]);
        asm volatile("s_barrier" ::: "memory");
        asm volatile("s_waitcnt vmcnt(0)" ::: "memory");   // V15 lands
        asm volatile("s_barrier" ::: "memory");
    }
    // ---- epilogue: last PV ----
    pv_step(15, pf[1]);

    // extract l (held at quad==0 lanes, col c) and broadcast to the wave
    float l_i[2];
    l_i[0] = __shfl(o[4][0][0], c);
    l_i[1] = __shfl(o[4][1][0], c);

    __syncthreads();   // PV(15) LDS reads done before aliasing cO over bufs
    // ---- combine the two KV-halves via LDS, group 0 writes out ----
    if (g == 1) {
#pragma unroll
        for (int nb = 0; nb < 2; ++nb) {
            int ql = ww * 32 + nb * 16 + c;
            if (quad == 0) { cml[ql] = m_i[nb]; cml[128 + ql] = l_i[nb]; }
#pragma unroll
            for (int db = 0; db < 4; ++db) {
                int d4 = db * 4 + quad;
                *(f32x4*)&cO[(ql * 16 + (d4 ^ (ql & 15))) << 2] = o[db][nb];
            }
        }
    }
    __syncthreads();
    if (g == 0) {
#pragma unroll
        for (int nb = 0; nb < 2; ++nb) {
            int ql = ww * 32 + nb * 16 + c;
            int qq = qt * 128 + ql;
            float m2 = cml[ql], l2 = cml[128 + ql];
            float mm = fmaxf(m_i[nb], m2);
            float a1 = __builtin_amdgcn_exp2f(m_i[nb] - mm);
            float a2 = __builtin_amdgcn_exp2f(m2 - mm);
            float linv = 1.f / (l_i[nb] * a1 + l2 * a2);
#pragma unroll
            for (int db = 0; db < 4; ++db) {
                int d4 = db * 4 + quad;
                f32x4 v2 = *(const f32x4*)&cO[(ql * 16 + (d4 ^ (ql & 15))) << 2];
                f32x4 v = (o[db][nb] * a1 + v2 * a2) * linv;
                *(f32x4*)(out + ((size_t)b * S_ + qq) * H_ + hh * 64 + db * 16 + quad * 4) = v;
            }
        }
    }
}

// ---------------- launch ----------------
extern "C" void kernel_launch(void* const* d_in, const int* in_sizes, int n_in,
                              void* d_out, int out_size, void* d_ws, size_t ws_size,
                              hipStream_t stream) {
    const float* query = (const float*)d_in[0];
    const float* key   = (const float*)d_in[1];
    const float* value = (const float*)d_in[2];
    const float* mask  = (const float*)d_in[3];
    const float* Wq    = (const float*)d_in[4];
    const float* bq    = (const float*)d_in[5];
    const float* Wk    = (const float*)d_in[6];
    const float* bk    = (const float*)d_in[7];
    const float* Wv    = (const float*)d_in[8];
    const float* bv    = (const float*)d_in[9];
    float* out = (float*)d_out;

    f16* p = (f16*)d_ws;
    f16* xq = p; p += SZX; f16* xk = p; p += SZX; f16* xv = p; p += SZX;
    f16* wq = p; p += SZW; f16* wk = p; p += SZW; f16* wv = p; p += SZW;
    f16* q  = p; p += SZX; f16* k  = p; p += SZX; f16* vt = p; p += SZX;
    float* mask_s = (float*)p;   // B_*S_ floats

    const int total = 3 * (int)(SZX / 4) + 3 * (int)(SZW / 4) + (B_ * S_ / 4);
    prep_kernel<<<(total + 255) / 256, 256, 0, stream>>>(
        query, key, value, Wq, Wk, Wv, mask, xq, xk, xv, wq, wk, wv, mask_s);

    proj_kernel<<<768, 256, 0, stream>>>(xq, xk, xv, wq, wk, wv, bq, bk, bv, q, k, vt);

    dim3 ag(512);
    attn_kernel<<<ag, 512, 0, stream>>>(q, k, vt, mask_s, out);
}